// Round 20
// baseline (1258.070 us; speedup 1.0000x reference)
//
#include <hip/hip_runtime.h>
#include <math.h>

#define T_ 8
#define B_ 4
#define CIN_ 3
#define H_ 30
#define W_ 32
#define HID_ 128
#define NPOS_ (H_*W_)          // 960
#define CHW_ (HID_*NPOS_)      // 122880
#define BCHW_ ((size_t)B_*CHW_)
#define LIN1_IN_ (HID_*NPOS_)  // 122880

// hsplit global layout (shorts): [b4][split2][chunk4][row36][kg4][col34][ci8]
#define HS_ROW_ 1088           // kg4*col34*ci8
#define HS_CH_  39168          // 36*HS_ROW_
#define HS_SLOT_ 1253376       // b4*s2*ch4*HS_CH_

typedef __attribute__((ext_vector_type(8))) short bs8;
typedef __attribute__((ext_vector_type(4))) float f32x4;
typedef unsigned int __attribute__((address_space(1))) gas_u32;
typedef unsigned int __attribute__((address_space(3))) las_u32;

__device__ __forceinline__ void gload16(const void* g, void* l) {
  __builtin_amdgcn_global_load_lds((const gas_u32*)g, (las_u32*)l, 16, 0, 0);
}

__device__ __forceinline__ unsigned short f2bf(float f) {
  unsigned u = __float_as_uint(f);
  return (unsigned short)((u + 0x7fffu + ((u >> 16) & 1u)) >> 16);
}
__device__ __forceinline__ float bf2f(unsigned short h) {
  return __uint_as_float(((unsigned)h) << 16);
}
__device__ __forceinline__ void split2(float v, unsigned short& h,
                                       unsigned short& m) {
  h = f2bf(v);
  m = f2bf(v - bf2f(h));
}

// ---------------------------------------------------------------------------
// Weight transform (identical to R17): single-bf16, grouped (ks,ky) layout:
// Wsp[g = ks*3+ky][mt][kx3][kg4][oc128][ci8]; oc low-4 bits XOR-swizzled.
// ---------------------------------------------------------------------------
__global__ __launch_bounds__(256)
void wsplit(const float* __restrict__ W, unsigned short* __restrict__ Wsp,
            int CTOT, int ci_off, int total)
{
  int i = blockIdx.x * 256 + threadIdx.x;
  if (i >= total) return;
  int ci8 = i & 7;
  int oc  = (i >> 3) & 127;
  int kg  = (i >> 10) & 3;
  int mtl = (i >> 12) & 3;
  int r   = i >> 14;            // phase = ks*9 + tap
  int tap = r % 9;
  int ks  = r / 9;
  int ky = tap / 3, kx = tap % 3;
  int g = ks * 3 + ky;
  int ocp = mtl * 128 + oc;
  int hid = ocp >> 2, gate = ocp & 3;
  int cio = ci_off + ks * 32 + kg * 8 + ci8;
  float v = W[((size_t)(gate * HID_ + hid) * CTOT + cio) * 9 + tap];
  int ocs = (oc & 0x70) | ((oc ^ (kg << 1)) & 0x0F);
  Wsp[((size_t)(g * 4 + mtl) * 3 + kx) * 4096 + kg * 1024 + ocs * 8 + ci8]
      = f2bf(v);
}

// Layer-0 x-part weights: Wxp[oc'(512)][ci3*9+tap] fp32
__global__ __launch_bounds__(256)
void wtx(const float* __restrict__ W0, float* __restrict__ Wxp)
{
  int i = blockIdx.x * 256 + threadIdx.x;
  if (i >= 512 * 27) return;
  int ocp = i / 27, rem = i % 27;
  int ci = rem / 9, tap = rem % 9;
  int hid = ocp >> 2, gate = ocp & 3;
  Wxp[i] = W0[((size_t)(gate * HID_ + hid) * 131 + ci) * 9 + tap];
}

// ---------------------------------------------------------------------------
// bf16-weight / 2-split-act MFMA fused conv + ConvLSTM (R17 structure).
// grid (4*n, 60), 256 thr. PHASE = one (ks,ky) group = 3 taps.
// NEW (T14): act staging for chunk c+1 is split — global loads issued during
// the LAST group of chunk c (hidden under 48 MFMAs), ds_writes after the
// boundary barrier. Removes the exposed L2 round-trip at 7 boundaries/step.
// ---------------------------------------------------------------------------
struct StepSlot {
  const unsigned short* Wsp;
  const float* Wxp;
  const unsigned short* xs;   // prev-layer hsplit slot (chunks 0..3) or null
  const unsigned short* hs;   // own hsplit slot (h chunks) or null
  const float* xraw;          // layer0 raw x or null
  const float* bias;
  float* hout;                // fp32 h out (only l3 t7) or null
  float* cbuf;
  unsigned short* hsout;      // own hsplit out slot
  int nchunk; int is_l0;
};
struct StepArgs { StepSlot s[4]; };

__global__ __launch_bounds__(256, 2)
void conv_mfma(StepArgs args)
{
  const int bx = blockIdx.x;
  const int mt = bx & 3;
  const StepSlot sl = args.s[bx >> 2];
  const int tid = threadIdx.x;
  const int nt = blockIdx.y;            // 0..59
  const int b  = nt / 15;
  const int y0 = (nt % 15) * 2;
  const int lane = tid & 63;
  const int wid = tid >> 6;
  const int wm = wid >> 1;
  const int wn = wid & 1;
  const int lanelo = lane & 15;
  const int kgl = lane >> 4;
  const int lsw = lanelo ^ (kgl << 1);

  // sact: [s2][r4][kg4][col34][ci8] = 8704 sh (17408B)
  // sW:   2 x [kx3][kg4][oc128][ci8] = 2 x 12288 sh (49152B)  total 66560B
  __shared__ __align__(16) unsigned short sact[8704];
  __shared__ __align__(16) unsigned short sW[2][12288];

  f32x4 acc[4][2];
  #pragma unroll
  for (int mf = 0; mf < 4; ++mf)
    #pragma unroll
    for (int nf = 0; nf < 2; ++nf)
      acc[mf][nf] = (f32x4){0.f, 0.f, 0.f, 0.f};

  // ---- layer-0 x-part (CIN=3) VALU pass ----
  if (sl.is_l0) {
    float* sWx = (float*)&sW[0][0];     // 13824B scratch (fits 24KB buf)
    for (int q = tid; q < 128 * 27; q += 256)
      sWx[q] = sl.Wxp[(size_t)mt * 128 * 27 + q];
    __syncthreads();
    const int y = y0 + wn;
    #pragma unroll
    for (int nf = 0; nf < 2; ++nf) {
      const int x = nf * 16 + lanelo;
      float xw[3][3][3];
      #pragma unroll
      for (int ci = 0; ci < 3; ++ci)
        #pragma unroll
        for (int ky = 0; ky < 3; ++ky)
          #pragma unroll
          for (int kx = 0; kx < 3; ++kx) {
            int yy = y + ky - 1, xx = x + kx - 1;
            xw[ci][ky][kx] = ((unsigned)yy < 30u && (unsigned)xx < 32u)
                ? sl.xraw[((size_t)(b * 3 + ci) * H_ + yy) * W_ + xx] : 0.f;
          }
      #pragma unroll
      for (int mf = 0; mf < 4; ++mf)
        #pragma unroll
        for (int g = 0; g < 4; ++g) {
          int oc = wm * 64 + mf * 16 + (kgl << 2) + g;
          float s = 0.f;
          #pragma unroll
          for (int ci = 0; ci < 3; ++ci)
            #pragma unroll
            for (int kk = 0; kk < 9; ++kk)
              s = fmaf(sWx[oc * 27 + ci * 9 + kk], xw[ci][kk / 3][kk % 3], s);
          acc[mf][nf][g] += s;
        }
    }
    __syncthreads();
  }

  const int NCH = sl.nchunk;

  // source pointer for chunk c's act panels
  auto actSrc = [&](int c, int s) -> const uint4* {
    const unsigned short* src; int ch;
    if (sl.xs) { if (c < 4) { src = sl.xs; ch = c; } else { src = sl.hs; ch = c - 4; } }
    else       { src = sl.hs; ch = c; }
    return (const uint4*)(src + (((size_t)b * 2 + s) * 4 + ch) * HS_CH_
                          + (size_t)y0 * HS_ROW_);
  };

  // inline load+write staging (used for chunk 0 prologue only)
  auto stageAct = [&](int c) {
    #pragma unroll
    for (int s = 0; s < 2; ++s) {
      const uint4* g = actSrc(c, s);
      uint4* d = (uint4*)(sact + s * 4352);
      for (int q = tid; q < 544; q += 256) d[q] = g[q];
    }
  };

  // stage one GROUP's weights (24KB = 3 kx panels) via global_load_lds
  auto stageW = [&](int g, int buf) {
    const char* src = (const char*)(sl.Wsp + (size_t)(g * 4 + mt) * 12288);
    char* d = (char*)&sW[buf][0];
    const int off = tid * 16;
    #pragma unroll
    for (int q = 0; q < 6; ++q)
      gload16(src + off + q * 4096, d + off + q * 4096);
  };

  if (NCH > 0) {
    stageAct(0);
    stageW(0, 0);
    __syncthreads();                    // stage(0) landed for all waves
    const int NG = NCH * 3;
    uint4 pa0[2], pa1[2], pa2[2];       // T14 act prefetch regs
    int g = 0;
    for (int c = 0; c < NCH; ++c) {
      #pragma unroll
      for (int kyg = 0; kyg < 3; ++kyg, ++g) {
        if (g > 0) {
          asm volatile("s_waitcnt vmcnt(0)");
          __builtin_amdgcn_s_barrier();
          __builtin_amdgcn_sched_barrier(0);
        }
        if (g + 1 < NG)                 // buffer (g+1)&1 freed by barrier
          stageW(g + 1, (g + 1) & 1);
        if (kyg == 2 && c + 1 < NCH) {  // T14: issue act loads for chunk c+1
          #pragma unroll
          for (int s = 0; s < 2; ++s) {
            const uint4* gp = actSrc(c + 1, s);
            pa0[s] = gp[tid];
            pa1[s] = gp[tid + 256];
            if (tid < 32) pa2[s] = gp[tid + 512];
          }
        }
        const bs8* Bv = (const bs8*)sact;
        const bs8* Aw = (const bs8*)&sW[g & 1][0];
        #pragma unroll
        for (int kx = 0; kx < 3; ++kx) {
          bs8 Bf[2][2];
          #pragma unroll
          for (int s = 0; s < 2; ++s)
            #pragma unroll
            for (int nf = 0; nf < 2; ++nf)
              Bf[s][nf] = Bv[((s * 4 + wn + kyg) * 4 + kgl) * 34
                             + nf * 16 + lanelo + kx];
          bs8 Af[4];
          #pragma unroll
          for (int mf = 0; mf < 4; ++mf)
            Af[mf] = Aw[kx * 512 + kgl * 128 + wm * 64 + mf * 16 + lsw];
          #pragma unroll
          for (int sb = 0; sb < 2; ++sb)
            #pragma unroll
            for (int mf = 0; mf < 4; ++mf)
              #pragma unroll
              for (int nf = 0; nf < 2; ++nf)
                acc[mf][nf] = __builtin_amdgcn_mfma_f32_16x16x32_bf16(
                    Af[mf], Bf[sb][nf], acc[mf][nf], 0, 0, 0);
        }
        __builtin_amdgcn_sched_barrier(0);
      }
      if (c + 1 < NCH) {
        __builtin_amdgcn_s_barrier();   // all waves done reading sact
        __builtin_amdgcn_sched_barrier(0);
        // T14: write prefetched act (loads already landed under the MFMAs)
        #pragma unroll
        for (int s = 0; s < 2; ++s) {
          uint4* d = (uint4*)(sact + s * 4352);
          d[tid] = pa0[s];
          d[tid + 256] = pa1[s];
          if (tid < 32) d[tid + 512] = pa2[s];
        }
        __syncthreads();                // ds_writes visible to all waves
      }
    }
  }

  // ---- in-register LSTM epilogue (y = y0+wn is always < 30) ----
  float hv[4][2];
  const int y = y0 + wn;
  #pragma unroll
  for (int mf = 0; mf < 4; ++mf) {
    const int hlo = wm * 16 + mf * 4 + kgl;
    const int hid = mt * 32 + hlo;
    const float b0 = sl.bias[hid];
    const float b1 = sl.bias[128 + hid];
    const float b2 = sl.bias[256 + hid];
    const float b3 = sl.bias[384 + hid];
    #pragma unroll
    for (int nf = 0; nf < 2; ++nf) {
      const int x = nf * 16 + lanelo;
      const size_t idx = ((size_t)(b * HID_ + hid) * H_ + y) * W_ + x;
      float vi = acc[mf][nf][0] + b0;
      float vf = acc[mf][nf][1] + b1;
      float vo = acc[mf][nf][2] + b2;
      float vg = acc[mf][nf][3] + b3;
      float ig = 1.f / (1.f + expf(-vi));
      float fg = 1.f / (1.f + expf(-vf));
      float og = 1.f / (1.f + expf(-vo));
      float gg = tanhf(vg);
      float cn = fg * sl.cbuf[idx] + ig * gg;
      sl.cbuf[idx] = cn;
      float hn = og * tanhf(cn);
      if (sl.hout) sl.hout[idx] = hn;
      hv[mf][nf] = hn;
    }
  }

  // ---- split h, store to fragment-ready global layout ----
  if (sl.hsout) {
    __syncthreads();                     // sact reads all done
    unsigned short* hl = sact;           // [s2][r2][kg4][x32][cl8] = 4096 sh
    #pragma unroll
    for (int mf = 0; mf < 4; ++mf) {
      const int hlo = wm * 16 + mf * 4 + kgl;
      const int kg = hlo >> 3, cl = hlo & 7;
      #pragma unroll
      for (int nf = 0; nf < 2; ++nf) {
        const int x = nf * 16 + lanelo;
        unsigned short hh, hm;
        split2(hv[mf][nf], hh, hm);
        int o = (wn * 4 + kg) * 256 + x * 8 + cl;
        hl[o] = hh; hl[o + 2048] = hm;
      }
    }
    __syncthreads();
    for (int q = tid; q < 512; q += 256) {
      int s = q >> 8, rem = q & 255;
      int r = rem >> 7, kg = (rem >> 5) & 3, x = rem & 31;
      uint4 v = *(const uint4*)&hl[(((s * 2 + r) * 4 + kg) * 32 + x) * 8];
      unsigned short* dst = sl.hsout
          + ((((size_t)b * 2 + s) * 4 + mt) * 36 + (y0 + r + 1)) * HS_ROW_
          + (kg * 34 + x + 1) * 8;
      *(uint4*)dst = v;
    }
  }
}

// ---------------------------------------------------------------------------
// lin1 split-K + finish + lin2 (unchanged)
// ---------------------------------------------------------------------------
__global__ __launch_bounds__(256)
void lin1_part(const float* __restrict__ h, const float* __restrict__ w,
               float* __restrict__ part)
{
  const int bid = blockIdx.x;
  const int o  = bid >> 3;
  const int ks = bid & 7;
  const int tid = threadIdx.x;
  const float4* w4 = (const float4*)(w + (size_t)o * LIN1_IN_) + ks * 3840;
  const float4* h4 = (const float4*)h + ks * 3840;
  float acc[4] = {0.f, 0.f, 0.f, 0.f};
  for (int i = tid; i < 3840; i += 256) {
    float4 wv = w4[i];
    #pragma unroll
    for (int b = 0; b < 4; ++b) {
      float4 hv = h4[(size_t)b * 30720 + i];
      acc[b] = fmaf(wv.x, hv.x, fmaf(wv.y, hv.y,
               fmaf(wv.z, hv.z, fmaf(wv.w, hv.w, acc[b]))));
    }
  }
  #pragma unroll
  for (int b = 0; b < 4; ++b)
    for (int m = 32; m; m >>= 1) acc[b] += __shfl_xor(acc[b], m);
  __shared__ float red[4][4];
  if ((tid & 63) == 0) {
    #pragma unroll
    for (int b = 0; b < 4; ++b) red[tid >> 6][b] = acc[b];
  }
  __syncthreads();
  if (tid == 0) {
    #pragma unroll
    for (int b = 0; b < 4; ++b) {
      float s = red[0][b] + red[1][b] + red[2][b] + red[3][b];
      part[((size_t)b * 256 + o) * 8 + ks] = s;
    }
  }
}

__global__ __launch_bounds__(256)
void lin1_finish(const float* __restrict__ part, const float* __restrict__ bias,
                 float* __restrict__ z1)
{
  int i = blockIdx.x * 256 + threadIdx.x;
  if (i < 1024) {
    int o = i & 255;
    float s = bias[o];
    #pragma unroll
    for (int k = 0; k < 8; ++k) s += part[(size_t)i * 8 + k];
    z1[i] = fmaxf(s, 0.f);
  }
}

__global__ __launch_bounds__(64)
void lin2_kernel(const float* __restrict__ z1, const float* __restrict__ w2,
                 const float* __restrict__ b2, float* __restrict__ out)
{
  const int lane = threadIdx.x;
  for (int p = 0; p < 8; ++p) {
    int j = p >> 2, b = p & 3;
    float acc = 0.f;
    for (int k = lane; k < 256; k += 64)
      acc = fmaf(z1[b * 256 + k], w2[j * 256 + k], acc);
    for (int m = 32; m; m >>= 1) acc += __shfl_xor(acc, m);
    if (lane == 0) out[p] = acc + b2[j];
  }
}

extern "C" void kernel_launch(void* const* d_in, const int* in_sizes, int n_in,
                              void* d_out, int out_size, void* d_ws, size_t ws_size,
                              hipStream_t stream) {
  const float* x = (const float*)d_in[0];
  const float* Wks[4] = {(const float*)d_in[1], (const float*)d_in[3],
                         (const float*)d_in[5], (const float*)d_in[7]};
  const float* bks[4] = {(const float*)d_in[2], (const float*)d_in[4],
                         (const float*)d_in[6], (const float*)d_in[8]};
  const float* lin1_w = (const float*)d_in[9];
  const float* lin1_b = (const float*)d_in[10];
  const float* lin2_w = (const float*)d_in[11];
  const float* lin2_b = (const float*)d_in[12];
  float* out = (float*)d_out;

  const int CTOTs[4] = {131, 256, 256, 256};
  const int NKS[4]   = {4, 8, 8, 8};

  // ---- workspace carve: bf16 regions first, then fp32 ----
  unsigned short* up = (unsigned short*)d_ws;
  unsigned short* wsp[4];
  for (int l = 0; l < 4; ++l) {
    wsp[l] = up;
    up += (size_t)NKS[l] * 9 * 4 * 4096;
  }
  unsigned short* hsr0 = up;
  unsigned short* hsr[4];
  for (int l = 0; l < 4; ++l) { hsr[l] = up; up += 2 * (size_t)HS_SLOT_; }
  float* fp = (float*)up;
  float* wxp = fp;   fp += 512 * 27;
  float* hlast = fp; fp += BCHW_;
  float* cbase = fp; fp += 4 * BCHW_;
  float* part = fp;  fp += 4 * 256 * 8;
  float* z1 = fp;    fp += 1024;

  // ---- one-time weight transforms ----
  wtx<<<dim3(54), dim3(256), 0, stream>>>(Wks[0], wxp);
  for (int l = 0; l < 4; ++l) {
    int total = NKS[l] * 9 * 4 * 4096;
    wsplit<<<dim3((total + 255) / 256), dim3(256), 0, stream>>>(
        Wks[l], wsp[l], CTOTs[l], (l == 0) ? 3 : 0, total);
  }
  // zero c buffers and hsplit rings (halo rows/cols must be 0)
  hipMemsetAsync(cbase, 0, 4 * BCHW_ * sizeof(float), stream);
  hipMemsetAsync(hsr0, 0, 8 * (size_t)HS_SLOT_ * sizeof(unsigned short), stream);

  // ---- diagonal wavefront over (layer, t) ----
  for (int d = 0; d <= 10; ++d) {
    StepArgs a;
    int n = 0;
    for (int l = 0; l < 4; ++l) {
      int t = d - l;
      if (t < 0 || t > 7) continue;
      StepSlot& s = a.s[n++];
      s.is_l0 = (l == 0);
      s.Wsp = wsp[l];
      s.Wxp = (l == 0) ? wxp : nullptr;
      s.xraw = (l == 0) ? x + (size_t)t * B_ * CIN_ * NPOS_ : nullptr;
      s.xs = (l == 0) ? nullptr : hsr[l - 1] + (size_t)(t & 1) * HS_SLOT_;
      s.hs = (t == 0) ? nullptr : hsr[l] + (size_t)((t - 1) & 1) * HS_SLOT_;
      s.bias = bks[l];
      s.hout = (l == 3 && t == 7) ? hlast : nullptr;
      s.cbuf = cbase + (size_t)l * BCHW_;
      s.hsout = hsr[l] + (size_t)(t & 1) * HS_SLOT_;
      s.nchunk = (l == 0) ? (t ? 4 : 0) : (t ? 8 : 4);
    }
    for (int z = n; z < 4; ++z) a.s[z] = a.s[0];
    conv_mfma<<<dim3(4 * n, 60), dim3(256), 0, stream>>>(a);
  }

  lin1_part<<<dim3(2048), dim3(256), 0, stream>>>(hlast, lin1_w, part);
  lin1_finish<<<dim3(4), dim3(256), 0, stream>>>(part, lin1_b, z1);
  lin2_kernel<<<dim3(1), dim3(64), 0, stream>>>(z1, lin2_w, lin2_b, out);
}

// Round 21
// 1096.965 us; speedup vs baseline: 1.1469x; 1.1469x over previous
//
#include <hip/hip_runtime.h>
#include <math.h>

#define T_ 8
#define B_ 4
#define CIN_ 3
#define H_ 30
#define W_ 32
#define HID_ 128
#define NPOS_ (H_*W_)          // 960
#define CHW_ (HID_*NPOS_)      // 122880
#define BCHW_ ((size_t)B_*CHW_)
#define LIN1_IN_ (HID_*NPOS_)  // 122880

// hsplit global layout (shorts): [b4][split2][chunk4][row36][kg4][col34][ci8]
#define HS_ROW_ 1088           // kg4*col34*ci8
#define HS_CH_  39168          // 36*HS_ROW_
#define HS_SLOT_ 1253376       // b4*s2*ch4*HS_CH_

typedef __attribute__((ext_vector_type(8))) short bs8;
typedef __attribute__((ext_vector_type(4))) float f32x4;
typedef unsigned int __attribute__((address_space(1))) gas_u32;
typedef unsigned int __attribute__((address_space(3))) las_u32;

__device__ __forceinline__ void gload16(const void* g, void* l) {
  __builtin_amdgcn_global_load_lds((const gas_u32*)g, (las_u32*)l, 16, 0, 0);
}

__device__ __forceinline__ unsigned short f2bf(float f) {
  unsigned u = __float_as_uint(f);
  return (unsigned short)((u + 0x7fffu + ((u >> 16) & 1u)) >> 16);
}
__device__ __forceinline__ float bf2f(unsigned short h) {
  return __uint_as_float(((unsigned)h) << 16);
}
__device__ __forceinline__ void split2(float v, unsigned short& h,
                                       unsigned short& m) {
  h = f2bf(v);
  m = f2bf(v - bf2f(h));
}

// ---------------------------------------------------------------------------
// Weight transform (R17): single-bf16, grouped (ks,ky) layout:
// Wsp[g = ks*3+ky][mt][kx3][kg4][oc128][ci8]; oc low-4 bits XOR-swizzled.
// ---------------------------------------------------------------------------
__global__ __launch_bounds__(256)
void wsplit(const float* __restrict__ W, unsigned short* __restrict__ Wsp,
            int CTOT, int ci_off, int total)
{
  int i = blockIdx.x * 256 + threadIdx.x;
  if (i >= total) return;
  int ci8 = i & 7;
  int oc  = (i >> 3) & 127;
  int kg  = (i >> 10) & 3;
  int mtl = (i >> 12) & 3;
  int r   = i >> 14;            // phase = ks*9 + tap
  int tap = r % 9;
  int ks  = r / 9;
  int ky = tap / 3, kx = tap % 3;
  int g = ks * 3 + ky;
  int ocp = mtl * 128 + oc;
  int hid = ocp >> 2, gate = ocp & 3;
  int cio = ci_off + ks * 32 + kg * 8 + ci8;
  float v = W[((size_t)(gate * HID_ + hid) * CTOT + cio) * 9 + tap];
  int ocs = (oc & 0x70) | ((oc ^ (kg << 1)) & 0x0F);
  Wsp[((size_t)(g * 4 + mtl) * 3 + kx) * 4096 + kg * 1024 + ocs * 8 + ci8]
      = f2bf(v);
}

// Layer-0 x-part weights: Wxp[oc'(512)][ci3*9+tap] fp32
__global__ __launch_bounds__(256)
void wtx(const float* __restrict__ W0, float* __restrict__ Wxp)
{
  int i = blockIdx.x * 256 + threadIdx.x;
  if (i >= 512 * 27) return;
  int ocp = i / 27, rem = i % 27;
  int ci = rem / 9, tap = rem % 9;
  int hid = ocp >> 2, gate = ocp & 3;
  Wxp[i] = W0[((size_t)(gate * HID_ + hid) * 131 + ci) * 9 + tap];
}

// ---------------------------------------------------------------------------
// bf16-weight / 2-split-act MFMA fused conv + ConvLSTM (R17 champion).
// grid (4*n, 60), 256 thr. PHASE = one (ks,ky) group = 3 taps: 24KB weight
// stage (dbuf, issue-early), 18 ds_read_b128 + 48 MFMA per wave-phase, one
// barrier quantum per phase. Only change vs R17: stageAct uses
// global_load_lds (linear dest) — no VGPR round-trip at chunk boundaries.
// ---------------------------------------------------------------------------
struct StepSlot {
  const unsigned short* Wsp;
  const float* Wxp;
  const unsigned short* xs;   // prev-layer hsplit slot (chunks 0..3) or null
  const unsigned short* hs;   // own hsplit slot (h chunks) or null
  const float* xraw;          // layer0 raw x or null
  const float* bias;
  float* hout;                // fp32 h out (only l3 t7) or null
  float* cbuf;
  unsigned short* hsout;      // own hsplit out slot
  int nchunk; int is_l0;
};
struct StepArgs { StepSlot s[4]; };

__global__ __launch_bounds__(256, 2)
void conv_mfma(StepArgs args)
{
  const int bx = blockIdx.x;
  const int mt = bx & 3;
  const StepSlot sl = args.s[bx >> 2];
  const int tid = threadIdx.x;
  const int nt = blockIdx.y;            // 0..59
  const int b  = nt / 15;
  const int y0 = (nt % 15) * 2;
  const int lane = tid & 63;
  const int wid = tid >> 6;
  const int wm = wid >> 1;
  const int wn = wid & 1;
  const int lanelo = lane & 15;
  const int kgl = lane >> 4;
  const int lsw = lanelo ^ (kgl << 1);

  // sact: [s2][r4][kg4][col34][ci8] = 8704 sh (17408B)
  // sW:   2 x [kx3][kg4][oc128][ci8] = 2 x 12288 sh (49152B)  total 66560B
  __shared__ __align__(16) unsigned short sact[8704];
  __shared__ __align__(16) unsigned short sW[2][12288];

  f32x4 acc[4][2];
  #pragma unroll
  for (int mf = 0; mf < 4; ++mf)
    #pragma unroll
    for (int nf = 0; nf < 2; ++nf)
      acc[mf][nf] = (f32x4){0.f, 0.f, 0.f, 0.f};

  // ---- layer-0 x-part (CIN=3) VALU pass ----
  if (sl.is_l0) {
    float* sWx = (float*)&sW[0][0];     // 13824B scratch (fits 24KB buf)
    for (int q = tid; q < 128 * 27; q += 256)
      sWx[q] = sl.Wxp[(size_t)mt * 128 * 27 + q];
    __syncthreads();
    const int y = y0 + wn;
    #pragma unroll
    for (int nf = 0; nf < 2; ++nf) {
      const int x = nf * 16 + lanelo;
      float xw[3][3][3];
      #pragma unroll
      for (int ci = 0; ci < 3; ++ci)
        #pragma unroll
        for (int ky = 0; ky < 3; ++ky)
          #pragma unroll
          for (int kx = 0; kx < 3; ++kx) {
            int yy = y + ky - 1, xx = x + kx - 1;
            xw[ci][ky][kx] = ((unsigned)yy < 30u && (unsigned)xx < 32u)
                ? sl.xraw[((size_t)(b * 3 + ci) * H_ + yy) * W_ + xx] : 0.f;
          }
      #pragma unroll
      for (int mf = 0; mf < 4; ++mf)
        #pragma unroll
        for (int g = 0; g < 4; ++g) {
          int oc = wm * 64 + mf * 16 + (kgl << 2) + g;
          float s = 0.f;
          #pragma unroll
          for (int ci = 0; ci < 3; ++ci)
            #pragma unroll
            for (int kk = 0; kk < 9; ++kk)
              s = fmaf(sWx[oc * 27 + ci * 9 + kk], xw[ci][kk / 3][kk % 3], s);
          acc[mf][nf][g] += s;
        }
    }
    __syncthreads();
  }

  const int NCH = sl.nchunk;

  // stage one chunk's 2 split panels via global_load_lds (linear dest:
  // offset = q*16 with q = tid, tid+256, tid<32 -> wave-uniform + lane*16)
  auto stageAct = [&](int c) {
    const unsigned short* src; int ch;
    if (sl.xs) { if (c < 4) { src = sl.xs; ch = c; } else { src = sl.hs; ch = c - 4; } }
    else       { src = sl.hs; ch = c; }
    #pragma unroll
    for (int s = 0; s < 2; ++s) {
      const char* g = (const char*)(src + (((size_t)b * 2 + s) * 4 + ch) * HS_CH_
                                    + (size_t)y0 * HS_ROW_);
      char* d = (char*)(sact + s * 4352);
      gload16(g + tid * 16, d + tid * 16);
      gload16(g + (256 + tid) * 16, d + (256 + tid) * 16);
      if (tid < 32) gload16(g + (512 + tid) * 16, d + (512 + tid) * 16);
    }
  };

  // stage one GROUP's weights (24KB = 3 kx panels) via global_load_lds
  auto stageW = [&](int g, int buf) {
    const char* src = (const char*)(sl.Wsp + (size_t)(g * 4 + mt) * 12288);
    char* d = (char*)&sW[buf][0];
    const int off = tid * 16;
    #pragma unroll
    for (int q = 0; q < 6; ++q)
      gload16(src + off + q * 4096, d + off + q * 4096);
  };

  if (NCH > 0) {
    stageAct(0);
    stageW(0, 0);
    __syncthreads();                    // stage(0) landed for all waves
    const int NG = NCH * 3;
    int g = 0;
    for (int c = 0; c < NCH; ++c) {
      #pragma unroll
      for (int kyg = 0; kyg < 3; ++kyg, ++g) {
        if (g > 0) {
          asm volatile("s_waitcnt vmcnt(0)");
          __builtin_amdgcn_s_barrier();
          __builtin_amdgcn_sched_barrier(0);
        }
        if (g + 1 < NG)                 // buffer (g+1)&1 freed by barrier
          stageW(g + 1, (g + 1) & 1);
        const bs8* Bv = (const bs8*)sact;
        const bs8* Aw = (const bs8*)&sW[g & 1][0];
        #pragma unroll
        for (int kx = 0; kx < 3; ++kx) {
          bs8 Bf[2][2];
          #pragma unroll
          for (int s = 0; s < 2; ++s)
            #pragma unroll
            for (int nf = 0; nf < 2; ++nf)
              Bf[s][nf] = Bv[((s * 4 + wn + kyg) * 4 + kgl) * 34
                             + nf * 16 + lanelo + kx];
          bs8 Af[4];
          #pragma unroll
          for (int mf = 0; mf < 4; ++mf)
            Af[mf] = Aw[kx * 512 + kgl * 128 + wm * 64 + mf * 16 + lsw];
          #pragma unroll
          for (int sb = 0; sb < 2; ++sb)
            #pragma unroll
            for (int mf = 0; mf < 4; ++mf)
              #pragma unroll
              for (int nf = 0; nf < 2; ++nf)
                acc[mf][nf] = __builtin_amdgcn_mfma_f32_16x16x32_bf16(
                    Af[mf], Bf[sb][nf], acc[mf][nf], 0, 0, 0);
        }
        __builtin_amdgcn_sched_barrier(0);
      }
      if (c + 1 < NCH) {
        __builtin_amdgcn_s_barrier();   // all waves done reading sact
        __builtin_amdgcn_sched_barrier(0);
        stageAct(c + 1);
        __syncthreads();                // drains act+weight loads
      }
    }
  }

  // ---- in-register LSTM epilogue (y = y0+wn is always < 30) ----
  float hv[4][2];
  const int y = y0 + wn;
  #pragma unroll
  for (int mf = 0; mf < 4; ++mf) {
    const int hlo = wm * 16 + mf * 4 + kgl;
    const int hid = mt * 32 + hlo;
    const float b0 = sl.bias[hid];
    const float b1 = sl.bias[128 + hid];
    const float b2 = sl.bias[256 + hid];
    const float b3 = sl.bias[384 + hid];
    #pragma unroll
    for (int nf = 0; nf < 2; ++nf) {
      const int x = nf * 16 + lanelo;
      const size_t idx = ((size_t)(b * HID_ + hid) * H_ + y) * W_ + x;
      float vi = acc[mf][nf][0] + b0;
      float vf = acc[mf][nf][1] + b1;
      float vo = acc[mf][nf][2] + b2;
      float vg = acc[mf][nf][3] + b3;
      float ig = 1.f / (1.f + expf(-vi));
      float fg = 1.f / (1.f + expf(-vf));
      float og = 1.f / (1.f + expf(-vo));
      float gg = tanhf(vg);
      float cn = fg * sl.cbuf[idx] + ig * gg;
      sl.cbuf[idx] = cn;
      float hn = og * tanhf(cn);
      if (sl.hout) sl.hout[idx] = hn;
      hv[mf][nf] = hn;
    }
  }

  // ---- split h, store to fragment-ready global layout ----
  if (sl.hsout) {
    __syncthreads();                     // sact reads all done
    unsigned short* hl = sact;           // [s2][r2][kg4][x32][cl8] = 4096 sh
    #pragma unroll
    for (int mf = 0; mf < 4; ++mf) {
      const int hlo = wm * 16 + mf * 4 + kgl;
      const int kg = hlo >> 3, cl = hlo & 7;
      #pragma unroll
      for (int nf = 0; nf < 2; ++nf) {
        const int x = nf * 16 + lanelo;
        unsigned short hh, hm;
        split2(hv[mf][nf], hh, hm);
        int o = (wn * 4 + kg) * 256 + x * 8 + cl;
        hl[o] = hh; hl[o + 2048] = hm;
      }
    }
    __syncthreads();
    for (int q = tid; q < 512; q += 256) {
      int s = q >> 8, rem = q & 255;
      int r = rem >> 7, kg = (rem >> 5) & 3, x = rem & 31;
      uint4 v = *(const uint4*)&hl[(((s * 2 + r) * 4 + kg) * 32 + x) * 8];
      unsigned short* dst = sl.hsout
          + ((((size_t)b * 2 + s) * 4 + mt) * 36 + (y0 + r + 1)) * HS_ROW_
          + (kg * 34 + x + 1) * 8;
      *(uint4*)dst = v;
    }
  }
}

// ---------------------------------------------------------------------------
// lin1 split-K + finish + lin2 (unchanged)
// ---------------------------------------------------------------------------
__global__ __launch_bounds__(256)
void lin1_part(const float* __restrict__ h, const float* __restrict__ w,
               float* __restrict__ part)
{
  const int bid = blockIdx.x;
  const int o  = bid >> 3;
  const int ks = bid & 7;
  const int tid = threadIdx.x;
  const float4* w4 = (const float4*)(w + (size_t)o * LIN1_IN_) + ks * 3840;
  const float4* h4 = (const float4*)h + ks * 3840;
  float acc[4] = {0.f, 0.f, 0.f, 0.f};
  for (int i = tid; i < 3840; i += 256) {
    float4 wv = w4[i];
    #pragma unroll
    for (int b = 0; b < 4; ++b) {
      float4 hv = h4[(size_t)b * 30720 + i];
      acc[b] = fmaf(wv.x, hv.x, fmaf(wv.y, hv.y,
               fmaf(wv.z, hv.z, fmaf(wv.w, hv.w, acc[b]))));
    }
  }
  #pragma unroll
  for (int b = 0; b < 4; ++b)
    for (int m = 32; m; m >>= 1) acc[b] += __shfl_xor(acc[b], m);
  __shared__ float red[4][4];
  if ((tid & 63) == 0) {
    #pragma unroll
    for (int b = 0; b < 4; ++b) red[tid >> 6][b] = acc[b];
  }
  __syncthreads();
  if (tid == 0) {
    #pragma unroll
    for (int b = 0; b < 4; ++b) {
      float s = red[0][b] + red[1][b] + red[2][b] + red[3][b];
      part[((size_t)b * 256 + o) * 8 + ks] = s;
    }
  }
}

__global__ __launch_bounds__(256)
void lin1_finish(const float* __restrict__ part, const float* __restrict__ bias,
                 float* __restrict__ z1)
{
  int i = blockIdx.x * 256 + threadIdx.x;
  if (i < 1024) {
    int o = i & 255;
    float s = bias[o];
    #pragma unroll
    for (int k = 0; k < 8; ++k) s += part[(size_t)i * 8 + k];
    z1[i] = fmaxf(s, 0.f);
  }
}

__global__ __launch_bounds__(64)
void lin2_kernel(const float* __restrict__ z1, const float* __restrict__ w2,
                 const float* __restrict__ b2, float* __restrict__ out)
{
  const int lane = threadIdx.x;
  for (int p = 0; p < 8; ++p) {
    int j = p >> 2, b = p & 3;
    float acc = 0.f;
    for (int k = lane; k < 256; k += 64)
      acc = fmaf(z1[b * 256 + k], w2[j * 256 + k], acc);
    for (int m = 32; m; m >>= 1) acc += __shfl_xor(acc, m);
    if (lane == 0) out[p] = acc + b2[j];
  }
}

extern "C" void kernel_launch(void* const* d_in, const int* in_sizes, int n_in,
                              void* d_out, int out_size, void* d_ws, size_t ws_size,
                              hipStream_t stream) {
  const float* x = (const float*)d_in[0];
  const float* Wks[4] = {(const float*)d_in[1], (const float*)d_in[3],
                         (const float*)d_in[5], (const float*)d_in[7]};
  const float* bks[4] = {(const float*)d_in[2], (const float*)d_in[4],
                         (const float*)d_in[6], (const float*)d_in[8]};
  const float* lin1_w = (const float*)d_in[9];
  const float* lin1_b = (const float*)d_in[10];
  const float* lin2_w = (const float*)d_in[11];
  const float* lin2_b = (const float*)d_in[12];
  float* out = (float*)d_out;

  const int CTOTs[4] = {131, 256, 256, 256};
  const int NKS[4]   = {4, 8, 8, 8};

  // ---- workspace carve: bf16 regions first, then fp32 ----
  unsigned short* up = (unsigned short*)d_ws;
  unsigned short* wsp[4];
  for (int l = 0; l < 4; ++l) {
    wsp[l] = up;
    up += (size_t)NKS[l] * 9 * 4 * 4096;
  }
  unsigned short* hsr0 = up;
  unsigned short* hsr[4];
  for (int l = 0; l < 4; ++l) { hsr[l] = up; up += 2 * (size_t)HS_SLOT_; }
  float* fp = (float*)up;
  float* wxp = fp;   fp += 512 * 27;
  float* hlast = fp; fp += BCHW_;
  float* cbase = fp; fp += 4 * BCHW_;
  float* part = fp;  fp += 4 * 256 * 8;
  float* z1 = fp;    fp += 1024;

  // ---- one-time weight transforms ----
  wtx<<<dim3(54), dim3(256), 0, stream>>>(Wks[0], wxp);
  for (int l = 0; l < 4; ++l) {
    int total = NKS[l] * 9 * 4 * 4096;
    wsplit<<<dim3((total + 255) / 256), dim3(256), 0, stream>>>(
        Wks[l], wsp[l], CTOTs[l], (l == 0) ? 3 : 0, total);
  }
  // zero c buffers and hsplit rings (halo rows/cols must be 0)
  hipMemsetAsync(cbase, 0, 4 * BCHW_ * sizeof(float), stream);
  hipMemsetAsync(hsr0, 0, 8 * (size_t)HS_SLOT_ * sizeof(unsigned short), stream);

  // ---- diagonal wavefront over (layer, t) ----
  for (int d = 0; d <= 10; ++d) {
    StepArgs a;
    int n = 0;
    for (int l = 0; l < 4; ++l) {
      int t = d - l;
      if (t < 0 || t > 7) continue;
      StepSlot& s = a.s[n++];
      s.is_l0 = (l == 0);
      s.Wsp = wsp[l];
      s.Wxp = (l == 0) ? wxp : nullptr;
      s.xraw = (l == 0) ? x + (size_t)t * B_ * CIN_ * NPOS_ : nullptr;
      s.xs = (l == 0) ? nullptr : hsr[l - 1] + (size_t)(t & 1) * HS_SLOT_;
      s.hs = (t == 0) ? nullptr : hsr[l] + (size_t)((t - 1) & 1) * HS_SLOT_;
      s.bias = bks[l];
      s.hout = (l == 3 && t == 7) ? hlast : nullptr;
      s.cbuf = cbase + (size_t)l * BCHW_;
      s.hsout = hsr[l] + (size_t)(t & 1) * HS_SLOT_;
      s.nchunk = (l == 0) ? (t ? 4 : 0) : (t ? 8 : 4);
    }
    for (int z = n; z < 4; ++z) a.s[z] = a.s[0];
    conv_mfma<<<dim3(4 * n, 60), dim3(256), 0, stream>>>(a);
  }

  lin1_part<<<dim3(2048), dim3(256), 0, stream>>>(hlast, lin1_w, part);
  lin1_finish<<<dim3(4), dim3(256), 0, stream>>>(part, lin1_b, z1);
  lin2_kernel<<<dim3(1), dim3(64), 0, stream>>>(z1, lin2_w, lin2_b, out);
}

// Round 22
// 1094.642 us; speedup vs baseline: 1.1493x; 1.0021x over previous
//
#include <hip/hip_runtime.h>
#include <math.h>

#define T_ 8
#define B_ 4
#define CIN_ 3
#define H_ 30
#define W_ 32
#define HID_ 128
#define NPOS_ (H_*W_)          // 960
#define CHW_ (HID_*NPOS_)      // 122880
#define BCHW_ ((size_t)B_*CHW_)
#define LIN1_IN_ (HID_*NPOS_)  // 122880

// hsplit global layout (shorts): [b4][split2][chunk4][row36][kg4][col34][ci8]
#define HS_ROW_ 1088           // kg4*col34*ci8
#define HS_CH_  39168          // 36*HS_ROW_
#define HS_SLOT_ 1253376       // b4*s2*ch4*HS_CH_

typedef __attribute__((ext_vector_type(8))) short bs8;
typedef __attribute__((ext_vector_type(4))) float f32x4;
typedef unsigned int __attribute__((address_space(1))) gas_u32;
typedef unsigned int __attribute__((address_space(3))) las_u32;

__device__ __forceinline__ void gload16(const void* g, void* l) {
  __builtin_amdgcn_global_load_lds((const gas_u32*)g, (las_u32*)l, 16, 0, 0);
}

__device__ __forceinline__ unsigned short f2bf(float f) {
  unsigned u = __float_as_uint(f);
  return (unsigned short)((u + 0x7fffu + ((u >> 16) & 1u)) >> 16);
}
__device__ __forceinline__ float bf2f(unsigned short h) {
  return __uint_as_float(((unsigned)h) << 16);
}
__device__ __forceinline__ void split2(float v, unsigned short& h,
                                       unsigned short& m) {
  h = f2bf(v);
  m = f2bf(v - bf2f(h));
}

// ---------------------------------------------------------------------------
// Weight transform (R17/R21): single-bf16, grouped (ks,ky) layout:
// Wsp[g = ks*3+ky][mt][kx3][kg4][oc128][ci8]; oc low-4 bits XOR-swizzled.
// ---------------------------------------------------------------------------
__global__ __launch_bounds__(256)
void wsplit(const float* __restrict__ W, unsigned short* __restrict__ Wsp,
            int CTOT, int ci_off, int total)
{
  int i = blockIdx.x * 256 + threadIdx.x;
  if (i >= total) return;
  int ci8 = i & 7;
  int oc  = (i >> 3) & 127;
  int kg  = (i >> 10) & 3;
  int mtl = (i >> 12) & 3;
  int r   = i >> 14;            // phase = ks*9 + tap
  int tap = r % 9;
  int ks  = r / 9;
  int ky = tap / 3, kx = tap % 3;
  int g = ks * 3 + ky;
  int ocp = mtl * 128 + oc;
  int hid = ocp >> 2, gate = ocp & 3;
  int cio = ci_off + ks * 32 + kg * 8 + ci8;
  float v = W[((size_t)(gate * HID_ + hid) * CTOT + cio) * 9 + tap];
  int ocs = (oc & 0x70) | ((oc ^ (kg << 1)) & 0x0F);
  Wsp[((size_t)(g * 4 + mtl) * 3 + kx) * 4096 + kg * 1024 + ocs * 8 + ci8]
      = f2bf(v);
}

// Layer-0 x-part weights: Wxp[oc'(512)][ci3*9+tap] fp32
__global__ __launch_bounds__(256)
void wtx(const float* __restrict__ W0, float* __restrict__ Wxp)
{
  int i = blockIdx.x * 256 + threadIdx.x;
  if (i >= 512 * 27) return;
  int ocp = i / 27, rem = i % 27;
  int ci = rem / 9, tap = rem % 9;
  int hid = ocp >> 2, gate = ocp & 3;
  Wxp[i] = W0[((size_t)(gate * HID_ + hid) * 131 + ci) * 9 + tap];
}

// ---------------------------------------------------------------------------
// bf16-weight / 2-split-act MFMA fused conv + ConvLSTM (R21 champion + T5).
// grid (4*n, 60), 256 thr. PHASE = one (ks,ky) group = 3 taps: 24KB weight
// stage (dbuf, issue-early), 24 ds_read_b128 + 48 MFMA per wave-phase, one
// barrier quantum per phase. T5: setprio(1) around the MFMA cluster — the
// two independent blocks/CU provide the wave-role diversity it needs.
// ---------------------------------------------------------------------------
struct StepSlot {
  const unsigned short* Wsp;
  const float* Wxp;
  const unsigned short* xs;   // prev-layer hsplit slot (chunks 0..3) or null
  const unsigned short* hs;   // own hsplit slot (h chunks) or null
  const float* xraw;          // layer0 raw x or null
  const float* bias;
  float* hout;                // fp32 h out (only l3 t7) or null
  float* cbuf;
  unsigned short* hsout;      // own hsplit out slot
  int nchunk; int is_l0;
};
struct StepArgs { StepSlot s[4]; };

__global__ __launch_bounds__(256, 2)
void conv_mfma(StepArgs args)
{
  const int bx = blockIdx.x;
  const int mt = bx & 3;
  const StepSlot sl = args.s[bx >> 2];
  const int tid = threadIdx.x;
  const int nt = blockIdx.y;            // 0..59
  const int b  = nt / 15;
  const int y0 = (nt % 15) * 2;
  const int lane = tid & 63;
  const int wid = tid >> 6;
  const int wm = wid >> 1;
  const int wn = wid & 1;
  const int lanelo = lane & 15;
  const int kgl = lane >> 4;
  const int lsw = lanelo ^ (kgl << 1);

  // sact: [s2][r4][kg4][col34][ci8] = 8704 sh (17408B)
  // sW:   2 x [kx3][kg4][oc128][ci8] = 2 x 12288 sh (49152B)  total 66560B
  __shared__ __align__(16) unsigned short sact[8704];
  __shared__ __align__(16) unsigned short sW[2][12288];

  f32x4 acc[4][2];
  #pragma unroll
  for (int mf = 0; mf < 4; ++mf)
    #pragma unroll
    for (int nf = 0; nf < 2; ++nf)
      acc[mf][nf] = (f32x4){0.f, 0.f, 0.f, 0.f};

  // ---- layer-0 x-part (CIN=3) VALU pass ----
  if (sl.is_l0) {
    float* sWx = (float*)&sW[0][0];     // 13824B scratch (fits 24KB buf)
    for (int q = tid; q < 128 * 27; q += 256)
      sWx[q] = sl.Wxp[(size_t)mt * 128 * 27 + q];
    __syncthreads();
    const int y = y0 + wn;
    #pragma unroll
    for (int nf = 0; nf < 2; ++nf) {
      const int x = nf * 16 + lanelo;
      float xw[3][3][3];
      #pragma unroll
      for (int ci = 0; ci < 3; ++ci)
        #pragma unroll
        for (int ky = 0; ky < 3; ++ky)
          #pragma unroll
          for (int kx = 0; kx < 3; ++kx) {
            int yy = y + ky - 1, xx = x + kx - 1;
            xw[ci][ky][kx] = ((unsigned)yy < 30u && (unsigned)xx < 32u)
                ? sl.xraw[((size_t)(b * 3 + ci) * H_ + yy) * W_ + xx] : 0.f;
          }
      #pragma unroll
      for (int mf = 0; mf < 4; ++mf)
        #pragma unroll
        for (int g = 0; g < 4; ++g) {
          int oc = wm * 64 + mf * 16 + (kgl << 2) + g;
          float s = 0.f;
          #pragma unroll
          for (int ci = 0; ci < 3; ++ci)
            #pragma unroll
            for (int kk = 0; kk < 9; ++kk)
              s = fmaf(sWx[oc * 27 + ci * 9 + kk], xw[ci][kk / 3][kk % 3], s);
          acc[mf][nf][g] += s;
        }
    }
    __syncthreads();
  }

  const int NCH = sl.nchunk;

  // stage one chunk's 2 split panels via global_load_lds (linear dest)
  auto stageAct = [&](int c) {
    const unsigned short* src; int ch;
    if (sl.xs) { if (c < 4) { src = sl.xs; ch = c; } else { src = sl.hs; ch = c - 4; } }
    else       { src = sl.hs; ch = c; }
    #pragma unroll
    for (int s = 0; s < 2; ++s) {
      const char* g = (const char*)(src + (((size_t)b * 2 + s) * 4 + ch) * HS_CH_
                                    + (size_t)y0 * HS_ROW_);
      char* d = (char*)(sact + s * 4352);
      gload16(g + tid * 16, d + tid * 16);
      gload16(g + (256 + tid) * 16, d + (256 + tid) * 16);
      if (tid < 32) gload16(g + (512 + tid) * 16, d + (512 + tid) * 16);
    }
  };

  // stage one GROUP's weights (24KB = 3 kx panels) via global_load_lds
  auto stageW = [&](int g, int buf) {
    const char* src = (const char*)(sl.Wsp + (size_t)(g * 4 + mt) * 12288);
    char* d = (char*)&sW[buf][0];
    const int off = tid * 16;
    #pragma unroll
    for (int q = 0; q < 6; ++q)
      gload16(src + off + q * 4096, d + off + q * 4096);
  };

  if (NCH > 0) {
    stageAct(0);
    stageW(0, 0);
    __syncthreads();                    // stage(0) landed for all waves
    const int NG = NCH * 3;
    int g = 0;
    for (int c = 0; c < NCH; ++c) {
      #pragma unroll
      for (int kyg = 0; kyg < 3; ++kyg, ++g) {
        if (g > 0) {
          asm volatile("s_waitcnt vmcnt(0)");
          __builtin_amdgcn_s_barrier();
          __builtin_amdgcn_sched_barrier(0);
        }
        if (g + 1 < NG)                 // buffer (g+1)&1 freed by barrier
          stageW(g + 1, (g + 1) & 1);
        const bs8* Bv = (const bs8*)sact;
        const bs8* Aw = (const bs8*)&sW[g & 1][0];
        __builtin_amdgcn_s_setprio(1);  // T5: favor MFMA-entering waves
        #pragma unroll
        for (int kx = 0; kx < 3; ++kx) {
          bs8 Bf[2][2];
          #pragma unroll
          for (int s = 0; s < 2; ++s)
            #pragma unroll
            for (int nf = 0; nf < 2; ++nf)
              Bf[s][nf] = Bv[((s * 4 + wn + kyg) * 4 + kgl) * 34
                             + nf * 16 + lanelo + kx];
          bs8 Af[4];
          #pragma unroll
          for (int mf = 0; mf < 4; ++mf)
            Af[mf] = Aw[kx * 512 + kgl * 128 + wm * 64 + mf * 16 + lsw];
          #pragma unroll
          for (int sb = 0; sb < 2; ++sb)
            #pragma unroll
            for (int mf = 0; mf < 4; ++mf)
              #pragma unroll
              for (int nf = 0; nf < 2; ++nf)
                acc[mf][nf] = __builtin_amdgcn_mfma_f32_16x16x32_bf16(
                    Af[mf], Bf[sb][nf], acc[mf][nf], 0, 0, 0);
        }
        __builtin_amdgcn_s_setprio(0);
        __builtin_amdgcn_sched_barrier(0);
      }
      if (c + 1 < NCH) {
        __builtin_amdgcn_s_barrier();   // all waves done reading sact
        __builtin_amdgcn_sched_barrier(0);
        stageAct(c + 1);
        __syncthreads();                // drains act+weight loads
      }
    }
  }

  // ---- in-register LSTM epilogue (y = y0+wn is always < 30) ----
  float hv[4][2];
  const int y = y0 + wn;
  #pragma unroll
  for (int mf = 0; mf < 4; ++mf) {
    const int hlo = wm * 16 + mf * 4 + kgl;
    const int hid = mt * 32 + hlo;
    const float b0 = sl.bias[hid];
    const float b1 = sl.bias[128 + hid];
    const float b2 = sl.bias[256 + hid];
    const float b3 = sl.bias[384 + hid];
    #pragma unroll
    for (int nf = 0; nf < 2; ++nf) {
      const int x = nf * 16 + lanelo;
      const size_t idx = ((size_t)(b * HID_ + hid) * H_ + y) * W_ + x;
      float vi = acc[mf][nf][0] + b0;
      float vf = acc[mf][nf][1] + b1;
      float vo = acc[mf][nf][2] + b2;
      float vg = acc[mf][nf][3] + b3;
      float ig = 1.f / (1.f + expf(-vi));
      float fg = 1.f / (1.f + expf(-vf));
      float og = 1.f / (1.f + expf(-vo));
      float gg = tanhf(vg);
      float cn = fg * sl.cbuf[idx] + ig * gg;
      sl.cbuf[idx] = cn;
      float hn = og * tanhf(cn);
      if (sl.hout) sl.hout[idx] = hn;
      hv[mf][nf] = hn;
    }
  }

  // ---- split h, store to fragment-ready global layout ----
  if (sl.hsout) {
    __syncthreads();                     // sact reads all done
    unsigned short* hl = sact;           // [s2][r2][kg4][x32][cl8] = 4096 sh
    #pragma unroll
    for (int mf = 0; mf < 4; ++mf) {
      const int hlo = wm * 16 + mf * 4 + kgl;
      const int kg = hlo >> 3, cl = hlo & 7;
      #pragma unroll
      for (int nf = 0; nf < 2; ++nf) {
        const int x = nf * 16 + lanelo;
        unsigned short hh, hm;
        split2(hv[mf][nf], hh, hm);
        int o = (wn * 4 + kg) * 256 + x * 8 + cl;
        hl[o] = hh; hl[o + 2048] = hm;
      }
    }
    __syncthreads();
    for (int q = tid; q < 512; q += 256) {
      int s = q >> 8, rem = q & 255;
      int r = rem >> 7, kg = (rem >> 5) & 3, x = rem & 31;
      uint4 v = *(const uint4*)&hl[(((s * 2 + r) * 4 + kg) * 32 + x) * 8];
      unsigned short* dst = sl.hsout
          + ((((size_t)b * 2 + s) * 4 + mt) * 36 + (y0 + r + 1)) * HS_ROW_
          + (kg * 34 + x + 1) * 8;
      *(uint4*)dst = v;
    }
  }
}

// ---------------------------------------------------------------------------
// lin1 split-K + finish + lin2 (unchanged)
// ---------------------------------------------------------------------------
__global__ __launch_bounds__(256)
void lin1_part(const float* __restrict__ h, const float* __restrict__ w,
               float* __restrict__ part)
{
  const int bid = blockIdx.x;
  const int o  = bid >> 3;
  const int ks = bid & 7;
  const int tid = threadIdx.x;
  const float4* w4 = (const float4*)(w + (size_t)o * LIN1_IN_) + ks * 3840;
  const float4* h4 = (const float4*)h + ks * 3840;
  float acc[4] = {0.f, 0.f, 0.f, 0.f};
  for (int i = tid; i < 3840; i += 256) {
    float4 wv = w4[i];
    #pragma unroll
    for (int b = 0; b < 4; ++b) {
      float4 hv = h4[(size_t)b * 30720 + i];
      acc[b] = fmaf(wv.x, hv.x, fmaf(wv.y, hv.y,
               fmaf(wv.z, hv.z, fmaf(wv.w, hv.w, acc[b]))));
    }
  }
  #pragma unroll
  for (int b = 0; b < 4; ++b)
    for (int m = 32; m; m >>= 1) acc[b] += __shfl_xor(acc[b], m);
  __shared__ float red[4][4];
  if ((tid & 63) == 0) {
    #pragma unroll
    for (int b = 0; b < 4; ++b) red[tid >> 6][b] = acc[b];
  }
  __syncthreads();
  if (tid == 0) {
    #pragma unroll
    for (int b = 0; b < 4; ++b) {
      float s = red[0][b] + red[1][b] + red[2][b] + red[3][b];
      part[((size_t)b * 256 + o) * 8 + ks] = s;
    }
  }
}

__global__ __launch_bounds__(256)
void lin1_finish(const float* __restrict__ part, const float* __restrict__ bias,
                 float* __restrict__ z1)
{
  int i = blockIdx.x * 256 + threadIdx.x;
  if (i < 1024) {
    int o = i & 255;
    float s = bias[o];
    #pragma unroll
    for (int k = 0; k < 8; ++k) s += part[(size_t)i * 8 + k];
    z1[i] = fmaxf(s, 0.f);
  }
}

__global__ __launch_bounds__(64)
void lin2_kernel(const float* __restrict__ z1, const float* __restrict__ w2,
                 const float* __restrict__ b2, float* __restrict__ out)
{
  const int lane = threadIdx.x;
  for (int p = 0; p < 8; ++p) {
    int j = p >> 2, b = p & 3;
    float acc = 0.f;
    for (int k = lane; k < 256; k += 64)
      acc = fmaf(z1[b * 256 + k], w2[j * 256 + k], acc);
    for (int m = 32; m; m >>= 1) acc += __shfl_xor(acc, m);
    if (lane == 0) out[p] = acc + b2[j];
  }
}

extern "C" void kernel_launch(void* const* d_in, const int* in_sizes, int n_in,
                              void* d_out, int out_size, void* d_ws, size_t ws_size,
                              hipStream_t stream) {
  const float* x = (const float*)d_in[0];
  const float* Wks[4] = {(const float*)d_in[1], (const float*)d_in[3],
                         (const float*)d_in[5], (const float*)d_in[7]};
  const float* bks[4] = {(const float*)d_in[2], (const float*)d_in[4],
                         (const float*)d_in[6], (const float*)d_in[8]};
  const float* lin1_w = (const float*)d_in[9];
  const float* lin1_b = (const float*)d_in[10];
  const float* lin2_w = (const float*)d_in[11];
  const float* lin2_b = (const float*)d_in[12];
  float* out = (float*)d_out;

  const int CTOTs[4] = {131, 256, 256, 256};
  const int NKS[4]   = {4, 8, 8, 8};

  // ---- workspace carve: bf16 regions first, then fp32 ----
  unsigned short* up = (unsigned short*)d_ws;
  unsigned short* wsp[4];
  for (int l = 0; l < 4; ++l) {
    wsp[l] = up;
    up += (size_t)NKS[l] * 9 * 4 * 4096;
  }
  unsigned short* hsr0 = up;
  unsigned short* hsr[4];
  for (int l = 0; l < 4; ++l) { hsr[l] = up; up += 2 * (size_t)HS_SLOT_; }
  float* fp = (float*)up;
  float* wxp = fp;   fp += 512 * 27;
  float* hlast = fp; fp += BCHW_;
  float* cbase = fp; fp += 4 * BCHW_;
  float* part = fp;  fp += 4 * 256 * 8;
  float* z1 = fp;    fp += 1024;

  // ---- one-time weight transforms ----
  wtx<<<dim3(54), dim3(256), 0, stream>>>(Wks[0], wxp);
  for (int l = 0; l < 4; ++l) {
    int total = NKS[l] * 9 * 4 * 4096;
    wsplit<<<dim3((total + 255) / 256), dim3(256), 0, stream>>>(
        Wks[l], wsp[l], CTOTs[l], (l == 0) ? 3 : 0, total);
  }
  // zero c buffers and hsplit rings (halo rows/cols must be 0)
  hipMemsetAsync(cbase, 0, 4 * BCHW_ * sizeof(float), stream);
  hipMemsetAsync(hsr0, 0, 8 * (size_t)HS_SLOT_ * sizeof(unsigned short), stream);

  // ---- diagonal wavefront over (layer, t) ----
  for (int d = 0; d <= 10; ++d) {
    StepArgs a;
    int n = 0;
    for (int l = 0; l < 4; ++l) {
      int t = d - l;
      if (t < 0 || t > 7) continue;
      StepSlot& s = a.s[n++];
      s.is_l0 = (l == 0);
      s.Wsp = wsp[l];
      s.Wxp = (l == 0) ? wxp : nullptr;
      s.xraw = (l == 0) ? x + (size_t)t * B_ * CIN_ * NPOS_ : nullptr;
      s.xs = (l == 0) ? nullptr : hsr[l - 1] + (size_t)(t & 1) * HS_SLOT_;
      s.hs = (t == 0) ? nullptr : hsr[l] + (size_t)((t - 1) & 1) * HS_SLOT_;
      s.bias = bks[l];
      s.hout = (l == 3 && t == 7) ? hlast : nullptr;
      s.cbuf = cbase + (size_t)l * BCHW_;
      s.hsout = hsr[l] + (size_t)(t & 1) * HS_SLOT_;
      s.nchunk = (l == 0) ? (t ? 4 : 0) : (t ? 8 : 4);
    }
    for (int z = n; z < 4; ++z) a.s[z] = a.s[0];
    conv_mfma<<<dim3(4 * n, 60), dim3(256), 0, stream>>>(a);
  }

  lin1_part<<<dim3(2048), dim3(256), 0, stream>>>(hlast, lin1_w, part);
  lin1_finish<<<dim3(4), dim3(256), 0, stream>>>(part, lin1_b, z1);
  lin2_kernel<<<dim3(1), dim3(64), 0, stream>>>(z1, lin2_w, lin2_b, out);
}